// Round 1
// baseline (579.992 us; speedup 1.0000x reference)
//
#include <hip/hip_runtime.h>

#define IN_DIM   320
#define POOL_DIM 256
#define HID      128
#define BM       64
#define BK       32

// ---------------------------------------------------------------------------
// Kernel A: scores = relu(z @ W1^T + b1) @ W2^T + b2      [N]
// Also emits per-block (max, sum(exp(s - max))) for the global softmax.
// Tile: BM=64 rows x HID=128 hidden, K chunked by BK=32.
// LDS float4 tiles XOR-swizzled on the k-quad index to kill bank conflicts.
// ---------------------------------------------------------------------------
__global__ __launch_bounds__(256) void attn_scores_kernel(
    const float* __restrict__ z, const float* __restrict__ W1,
    const float* __restrict__ b1, const float* __restrict__ W2,
    const float* __restrict__ b2,
    float* __restrict__ scores, float* __restrict__ bmax,
    float* __restrict__ bsum, int N)
{
    __shared__ float4 zs4[BM][8];    // zs4[row][q ^ (row&7)]
    __shared__ float4 ws4[HID][8];   // ws4[h][q ^ (h&7)]
    __shared__ float  sblk[BM];

    const int tid = threadIdx.x;
    const int tx  = tid & 15;        // h-lane (16)
    const int ty  = tid >> 4;        // row-group (16)
    const int r0  = blockIdx.x * BM;

    float acc[4][8];
#pragma unroll
    for (int a = 0; a < 4; a++)
#pragma unroll
        for (int b = 0; b < 8; b++) acc[a][b] = 0.f;

    for (int kc = 0; kc < IN_DIM / BK; kc++) {
        const int k0 = kc * BK;

        // ---- stage z tile: 64 rows x 8 quads = 512 float4, 2 per thread
#pragma unroll
        for (int i = 0; i < 2; i++) {
            int t   = tid + i * 256;
            int row = t >> 3;
            int q   = t & 7;
            int gr  = r0 + row;
            float4 v = make_float4(0.f, 0.f, 0.f, 0.f);
            if (gr < N)
                v = *(const float4*)&z[(size_t)gr * IN_DIM + k0 + q * 4];
            zs4[row][q ^ (row & 7)] = v;
        }
        // ---- stage W1 tile: 128 rows x 8 quads = 1024 float4, 4 per thread
#pragma unroll
        for (int i = 0; i < 4; i++) {
            int t = tid + i * 256;
            int h = t >> 3;
            int q = t & 7;
            float4 v = *(const float4*)&W1[(size_t)h * IN_DIM + k0 + q * 4];
            ws4[h][q ^ (h & 7)] = v;
        }
        __syncthreads();

        // ---- compute: per thread 4 rows x 8 h
#pragma unroll
        for (int q = 0; q < 8; q++) {
            float4 za[4], wb[8];
#pragma unroll
            for (int rr = 0; rr < 4; rr++) {
                int row = ty * 4 + rr;
                za[rr] = zs4[row][q ^ (row & 7)];
            }
#pragma unroll
            for (int hh = 0; hh < 8; hh++) {
                wb[hh] = ws4[hh * 16 + tx][q ^ (tx & 7)];
            }
#pragma unroll
            for (int rr = 0; rr < 4; rr++)
#pragma unroll
                for (int hh = 0; hh < 8; hh++) {
                    acc[rr][hh] += za[rr].x * wb[hh].x + za[rr].y * wb[hh].y +
                                   za[rr].z * wb[hh].z + za[rr].w * wb[hh].w;
                }
        }
        __syncthreads();
    }

    // ---- epilogue: relu, dot with W2, reduce over the 16 tx lanes
    float b1v[8], w2v[8];
#pragma unroll
    for (int hh = 0; hh < 8; hh++) {
        b1v[hh] = b1[hh * 16 + tx];
        w2v[hh] = W2[hh * 16 + tx];
    }
    const float b2v = b2[0];

#pragma unroll
    for (int rr = 0; rr < 4; rr++) {
        float s = 0.f;
#pragma unroll
        for (int hh = 0; hh < 8; hh++) {
            float hv = acc[rr][hh] + b1v[hh];
            s += fmaxf(hv, 0.f) * w2v[hh];
        }
#pragma unroll
        for (int d = 1; d < 16; d <<= 1) s += __shfl_xor(s, d, 16);
        s += b2v;
        if (tx == 0) {
            int r = ty * 4 + rr;
            if (r0 + r < N) {
                scores[r0 + r] = s;
                sblk[r] = s;
            } else {
                sblk[r] = -1e30f;   // neutral for max; exp() -> 0
            }
        }
    }
    __syncthreads();

    // ---- block (max, sum-exp): 64 scores = exactly one wave
    if (tid < 64) {
        float v = sblk[tid];
        float m = v;
#pragma unroll
        for (int d = 1; d < 64; d <<= 1) m = fmaxf(m, __shfl_xor(m, d, 64));
        float e = __expf(v - m);
        float ssum = e;
#pragma unroll
        for (int d = 1; d < 64; d <<= 1) ssum += __shfl_xor(ssum, d, 64);
        if (tid == 0) {
            bmax[blockIdx.x] = m;
            bsum[blockIdx.x] = ssum;
        }
    }
}

// ---------------------------------------------------------------------------
// Kernel B: combine per-block (max, sumexp) -> global max & softmax denom
// Single block; deterministic tree reductions.
// ---------------------------------------------------------------------------
__global__ __launch_bounds__(256) void softmax_reduce_kernel(
    const float* __restrict__ bmax, const float* __restrict__ bsum,
    float* __restrict__ red, int nb)
{
    __shared__ float sm[4];
    __shared__ float ss[4];
    const int tid = threadIdx.x;

    float m = -1e30f;
    for (int i = tid; i < nb; i += 256) m = fmaxf(m, bmax[i]);
#pragma unroll
    for (int d = 1; d < 64; d <<= 1) m = fmaxf(m, __shfl_xor(m, d, 64));
    if ((tid & 63) == 0) sm[tid >> 6] = m;
    __syncthreads();
    const float gmax = fmaxf(fmaxf(sm[0], sm[1]), fmaxf(sm[2], sm[3]));

    float s = 0.f;
    for (int i = tid; i < nb; i += 256) s += bsum[i] * __expf(bmax[i] - gmax);
#pragma unroll
    for (int d = 1; d < 64; d <<= 1) s += __shfl_xor(s, d, 64);
    if ((tid & 63) == 0) ss[tid >> 6] = s;
    __syncthreads();
    if (tid == 0) {
        red[0] = gmax;
        red[1] = ss[0] + ss[1] + ss[2] + ss[3];
    }
}

// ---------------------------------------------------------------------------
// Kernel E: per-graph weighted mean.  batch_index is sorted -> binary search
// the [start, end) row range; one block per graph, one thread per column.
// ---------------------------------------------------------------------------
__device__ __forceinline__ int lower_bound(const int* __restrict__ a, int n, int key)
{
    int lo = 0, hi = n;
    while (lo < hi) {
        int mid = (lo + hi) >> 1;
        if (a[mid] < key) lo = mid + 1; else hi = mid;
    }
    return lo;
}

__global__ __launch_bounds__(256) void pool_kernel(
    const float* __restrict__ z, const int* __restrict__ bidx,
    const float* __restrict__ scores, const float* __restrict__ red,
    float* __restrict__ out, int N)
{
    const int g   = blockIdx.x;
    const int col = threadIdx.x;
    __shared__ int se[2];
    if (col == 0) {
        se[0] = lower_bound(bidx, N, g);
        se[1] = lower_bound(bidx, N, g + 1);
    }
    __syncthreads();
    const int start = se[0], end = se[1];
    const float gmax    = red[0];
    const float inv_den = 1.0f / red[1];

    float acc0 = 0.f, acc1 = 0.f;
    int i = start;
    for (; i + 1 < end; i += 2) {
        float w0 = __expf(scores[i]     - gmax) * inv_den;
        float w1 = __expf(scores[i + 1] - gmax) * inv_den;
        acc0 += w0 * z[(size_t)i * IN_DIM + col];
        acc1 += w1 * z[(size_t)(i + 1) * IN_DIM + col];
    }
    if (i < end) {
        float w = __expf(scores[i] - gmax) * inv_den;
        acc0 += w * z[(size_t)i * IN_DIM + col];
    }
    const float acc = acc0 + acc1;
    const int cnt = end - start;
    out[(size_t)g * POOL_DIM + col] = acc / fmaxf((float)cnt, 1.0f);
}

// ---------------------------------------------------------------------------
extern "C" void kernel_launch(void* const* d_in, const int* in_sizes, int n_in,
                              void* d_out, int out_size, void* d_ws, size_t ws_size,
                              hipStream_t stream)
{
    const float* z    = (const float*)d_in[0];
    const int*   bidx = (const int*)  d_in[1];
    const float* W1   = (const float*)d_in[2];
    const float* b1   = (const float*)d_in[3];
    const float* W2   = (const float*)d_in[4];
    const float* b2   = (const float*)d_in[5];
    float*       out  = (float*)d_out;

    const int N  = in_sizes[0] / IN_DIM;       // 200000
    const int G  = out_size / POOL_DIM;        // 2000
    const int nb = (N + BM - 1) / BM;          // 3125

    float* scores = (float*)d_ws;
    float* bmax   = scores + N;
    float* bsum   = bmax + nb;
    float* red    = bsum + nb;

    attn_scores_kernel<<<nb, 256, 0, stream>>>(z, W1, b1, W2, b2,
                                               scores, bmax, bsum, N);
    softmax_reduce_kernel<<<1, 256, 0, stream>>>(bmax, bsum, red, nb);
    pool_kernel<<<G, 256, 0, stream>>>(z, bidx, scores, red, out, N);
}